// Round 12
// baseline (47.829 us; speedup 1.0000x reference)
//
#include <hip/hip_runtime.h>
#include <hip/hip_bf16.h>

// out[b,n] = sum_k x[b,k] * weight[indices[n],k]
// M=64, N=4403, K=4096, fp32 in/out.
// R12: compute is 0.27us/CU -- pure memory problem. Kill ALL aux structure:
// KSPLIT=1, NTILE=16, 276 blocks. Each block streams its 16 gathered rows x
// K=4096 (256KB) through a 2x32KB f32 LDS dbuf via global_load_lds, 8-chunk
// m97-style pipeline (stage k+1 + preload a-frags k+1 fly under compute k).
// One f32x4 acc/wave written DIRECTLY to out: no partials, no reduce kernel,
// no second dispatch gap. Swizzle = R9's proven both-sides XOR (row&7)<<4.

#define HIDDEN 4096
#define NCHUNKS 8
#define KCHUNK  512
#define KSTEPS  16                 // KCHUNK/32
#define BATCH   64
#define NTILE   16
#define NTILES  276                // ceil(4403/16)
#define XBF_OFF (16u << 20)        // byte offset of x_bf16 inside ws

using short8 = __attribute__((ext_vector_type(8))) short;
using f32x4  = __attribute__((ext_vector_type(4))) float;

typedef const void __attribute__((address_space(1))) gvoid;
typedef void __attribute__((address_space(3))) svoid;

__device__ __forceinline__ short f2bf(float f) {
    __bf16 h = (__bf16)f;                 // pairs into v_cvt_pk_bf16_f32
    return __builtin_bit_cast(short, h);
}

__device__ __forceinline__ short8 cvt8(const f32x4& lo, const f32x4& hi) {
    short8 r;
    r[0] = f2bf(lo[0]); r[1] = f2bf(lo[1]); r[2] = f2bf(lo[2]); r[3] = f2bf(lo[3]);
    r[4] = f2bf(hi[0]); r[5] = f2bf(hi[1]); r[6] = f2bf(hi[2]); r[7] = f2bf(hi[3]);
    return r;
}

// ---- k0: convert x to bf16 -------------------------------------------------
__global__ __launch_bounds__(256) void cvt_x(
    const float* __restrict__ x, unsigned short* __restrict__ xbf)
{
    const int i = (blockIdx.x * 256 + threadIdx.x) * 8;
    f32x4 a = *(const f32x4*)(x + i);
    f32x4 b = *(const f32x4*)(x + i + 4);
    *(short8*)(xbf + i) = cvt8(a, b);
}

// ---- k1: gathered GEMM, full-K per block, dbuf gload_lds pipeline ----------
__global__ __launch_bounds__(256, 2) void gather_gemm(
    const float*          __restrict__ weight,   // [11008, 4096] f32
    const unsigned short* __restrict__ xbf,      // [64, 4096] bf16
    const int*            __restrict__ indices,  // [R]
    float*                __restrict__ out,      // [64, R]
    int R)
{
    __shared__ float wlds[2][NTILE * KCHUNK];    // 2 x 32 KB

    const int t    = threadIdx.x;
    const int lane = t & 63;
    const int wave = t >> 6;
    const int nl   = lane & 15;
    const int kg   = lane >> 4;
    const int nb   = blockIdx.x;

    // per-wave staging rows (4 rows each), bases loaded once
    const char* rowp[4];
#pragma unroll
    for (int j = 0; j < 4; ++j) {
        const int n  = nb * NTILE + wave * 4 + j;
        const int wr = indices[n < R ? n : R - 1];
        rowp[j] = (const char*)(weight + (size_t)wr * HIDDEN);
    }

    const unsigned short* xrow =
        xbf + (size_t)(wave * 16 + nl) * HIDDEN + kg * 8;

    // stage chunk kb into buffer buf: LDS dest linear (wave-uniform + lane*16),
    // global source pre-swizzled: glb[g] -> LDS[g ^ ((row&7)<<4)]
#define STAGE(buf, kb)                                                         \
    {                                                                          \
        _Pragma("unroll")                                                      \
        for (int j = 0; j < 4; ++j) {                                          \
            const int r = wave * 4 + j;                                        \
            const unsigned int swz = (unsigned int)((r & 7) << 4);             \
            _Pragma("unroll")                                                  \
            for (int h = 0; h < 2; ++h) {                                      \
                const unsigned int srcoff =                                    \
                    ((unsigned int)(h * 1024 + lane * 16)) ^ swz;              \
                __builtin_amdgcn_global_load_lds(                              \
                    (gvoid*)(rowp[j] + (size_t)(kb) * 2048 + srcoff),          \
                    (svoid*)((char*)wlds[buf] + r * 2048 + h * 1024),          \
                    16, 0, 0);                                                 \
            }                                                                  \
        }                                                                      \
    }

#define PRE(afr, kb)                                                           \
    {                                                                          \
        _Pragma("unroll")                                                      \
        for (int ks = 0; ks < KSTEPS; ++ks)                                    \
            afr[ks] = *(const short8*)(xrow + (kb) * KCHUNK + ks * 32);        \
    }

    // consume buffer buf: per K-step {2 swizzled ds_read_b128 + cvt + 1 MFMA}
#define COMPUTE(buf, afr)                                                      \
    {                                                                          \
        const char* rowbase = (const char*)wlds[buf] + nl * 2048;              \
        const unsigned int swz = (unsigned int)((nl & 7) << 4);                \
        _Pragma("unroll")                                                      \
        for (int ks = 0; ks < KSTEPS; ++ks) {                                  \
            const unsigned int g0 = (unsigned int)(ks * 128 + kg * 32);        \
            f32x4 w0 = *(const f32x4*)(rowbase + (g0 ^ swz));                  \
            f32x4 w1 = *(const f32x4*)(rowbase + ((g0 + 16) ^ swz));           \
            short8 b = cvt8(w0, w1);                                           \
            acc = __builtin_amdgcn_mfma_f32_16x16x32_bf16(afr[ks], b, acc,     \
                                                          0, 0, 0);            \
        }                                                                      \
    }

    f32x4 acc = {0.f, 0.f, 0.f, 0.f};
    short8 afrA[KSTEPS], afrB[KSTEPS];

    STAGE(0, 0);
    PRE(afrA, 0);
    __syncthreads();

#pragma unroll
    for (int kb = 0; kb < NCHUNKS; kb += 2) {
        if (kb + 1 < NCHUNKS) { STAGE(1, kb + 1); PRE(afrB, kb + 1); }
        COMPUTE(0, afrA);
        __syncthreads();
        if (kb + 2 < NCHUNKS) { STAGE(0, kb + 2); PRE(afrA, kb + 2); }
        if (kb + 1 < NCHUNKS) {
            COMPUTE(1, afrB);
            __syncthreads();
        }
    }

#undef STAGE
#undef PRE
#undef COMPUTE

    // direct store: C/D col = nl (n), row = kg*4 + r within wave's 16 batch
    const int n = nb * NTILE + nl;
    if (n < R) {
#pragma unroll
        for (int r = 0; r < 4; ++r) {
            const int brow = wave * 16 + kg * 4 + r;
            out[(size_t)brow * R + n] = acc[r];
        }
    }
}

extern "C" void kernel_launch(void* const* d_in, const int* in_sizes, int n_in,
                              void* d_out, int out_size, void* d_ws, size_t ws_size,
                              hipStream_t stream) {
    const float* x       = (const float*)d_in[0];
    const float* weight  = (const float*)d_in[1];
    const int*   indices = (const int*)d_in[2];
    float*       out     = (float*)d_out;
    unsigned short* xbf  = (unsigned short*)((char*)d_ws + XBF_OFF);

    const int R = in_sizes[2];                    // 4403

    cvt_x<<<dim3((BATCH * HIDDEN) / (256 * 8)), dim3(256), 0, stream>>>(x, xbf);
    gather_gemm<<<dim3(NTILES), dim3(256), 0, stream>>>(weight, xbf, indices, out, R);
}

// Round 13
// 44.687 us; speedup vs baseline: 1.0703x; 1.0703x over previous
//
#include <hip/hip_runtime.h>
#include <hip/hip_bf16.h>

// out[b,n] = sum_k x[b,k] * weight[indices[n],k]
// M=64, N=4403, K=4096, fp32 in/out.
// R13: R6's GEMM (best: 1104 blocks, 4 blocks/CU, 32KB bf16 LDS, XOR swz)
// kept byte-for-byte, but cvt_x kernel DELETED: x loaded f32 + converted
// in-register during a-frag preload (R10 phase-1 proved this pattern).
// 2-dispatch pipeline: gemm -> reduce. Saves cvt dispatch + gap + xbf
// round-trip (~3us of the ~10us aux tax).

#define HIDDEN 4096
#define KSPLIT 8
#define KCHUNK (HIDDEN / KSPLIT)   // 512
#define KSTEPS (KCHUNK / 32)       // 16
#define BATCH  64
#define NTILE  32

using short8 = __attribute__((ext_vector_type(8))) short;
using f32x4  = __attribute__((ext_vector_type(4))) float;

__device__ __forceinline__ short f2bf(float f) {
    __bf16 h = (__bf16)f;                 // pairs into v_cvt_pk_bf16_f32
    return __builtin_bit_cast(short, h);
}

__device__ __forceinline__ short8 cvt8(const f32x4& lo, const f32x4& hi) {
    short8 r;
    r[0] = f2bf(lo[0]); r[1] = f2bf(lo[1]); r[2] = f2bf(lo[2]); r[3] = f2bf(lo[3]);
    r[4] = f2bf(hi[0]); r[5] = f2bf(hi[1]); r[6] = f2bf(hi[2]); r[7] = f2bf(hi[3]);
    return r;
}

// ---- k1: gathered GEMM, weight staged in LDS (R6 body, fused x-cvt) --------
__global__ __launch_bounds__(256, 4) void gather_gemm(
    const float* __restrict__ weight,   // [11008, 4096] f32
    const float* __restrict__ x,        // [64, 4096] f32
    const int*   __restrict__ indices,  // [R]
    float*       __restrict__ ws,       // [KSPLIT, 64, R] partials
    int R)
{
    __shared__ unsigned short wlds[NTILE * KCHUNK];   // 32 KB, XOR-swizzled

    const int t    = threadIdx.x;
    const int lane = t & 63;
    const int wave = t >> 6;       // 0..3 -> M-tile (16 batch rows each)
    const int nl   = lane & 15;
    const int kg   = lane >> 4;
    const int nb   = blockIdx.x;   // N-tile of 32
    const int kb   = blockIdx.y;   // K-chunk of 512
    const int k0   = kb * KCHUNK;

    // ---- stage weight tile rows nb*32..+31, cols k0..+511, bf16 + XOR swz --
    // 8 threads/row; thread covers cols (t&7)*8 + s*64 (8 f32 -> one b128)
    {
        const int r   = t >> 3;
        const int c   = t & 7;
        const int n   = nb * NTILE + r;
        const int row = indices[n < R ? n : R - 1];
        const float* src = weight + (size_t)row * HIDDEN + k0 + c * 8;
        char* ldsrow = (char*)wlds + r * (KCHUNK * 2);
        const unsigned int swz = (unsigned int)((r & 7) << 4);
#pragma unroll
        for (int s = 0; s < 8; ++s) {
            f32x4 v0 = *(const f32x4*)(src + (size_t)s * 64);
            f32x4 v1 = *(const f32x4*)(src + (size_t)s * 64 + 4);
            short8 h = cvt8(v0, v1);
            const unsigned int bc = (unsigned int)(c * 16 + s * 128);
            *(short8*)(ldsrow + (bc ^ swz)) = h;
        }
    }

    // ---- preload a-frags: x f32 -> cvt -> 16 x short8 (fused, no cvt_x) ----
    const float* xrow = x + (size_t)(wave * 16 + nl) * HIDDEN + k0 + kg * 8;
    short8 afr[KSTEPS];
#pragma unroll
    for (int ks = 0; ks < KSTEPS; ++ks) {
        f32x4 xa = *(const f32x4*)(xrow + ks * 32);
        f32x4 xb = *(const f32x4*)(xrow + ks * 32 + 4);
        afr[ks] = cvt8(xa, xb);
    }

    __syncthreads();

    // ---- K loop: 2 swizzled ds_read_b128 + 2 MFMA per step -----------------
    f32x4 acc0 = {0.f,0.f,0.f,0.f}, acc1 = {0.f,0.f,0.f,0.f};

#pragma unroll
    for (int ks = 0; ks < KSTEPS; ++ks) {
#pragma unroll
        for (int nf = 0; nf < 2; ++nf) {
            const int rr = nf * 16 + nl;
            const unsigned int bc =
                (unsigned int)(ks * 64 + kg * 16) ^ (unsigned int)((rr & 7) << 4);
            short8 b = *(const short8*)((const char*)wlds + rr * (KCHUNK * 2) + bc);
            f32x4& acc = nf == 0 ? acc0 : acc1;
            acc = __builtin_amdgcn_mfma_f32_16x16x32_bf16(afr[ks], b, acc, 0, 0, 0);
        }
    }

    // ---- store partials: C/D col = nl (n), row = kg*4 + r (batch) ----------
    float* part = ws + (size_t)kb * BATCH * R;
    f32x4 accs[2] = {acc0, acc1};
#pragma unroll
    for (int nf = 0; nf < 2; ++nf) {
        const int nn = nb * NTILE + nf * 16 + nl;
        if (nn < R) {
#pragma unroll
            for (int r = 0; r < 4; ++r) {
                const int brow = wave * 16 + kg * 4 + r;
                part[(size_t)brow * R + nn] = accs[nf][r];
            }
        }
    }
}

// ---- k2: sum KSPLIT partials ----------------------------------------------
__global__ __launch_bounds__(256) void reduce_partials(
    const float* __restrict__ ws, float* __restrict__ out, int n4, int stride4)
{
    const int i = blockIdx.x * blockDim.x + threadIdx.x;
    if (i >= n4) return;
    const f32x4* w = (const f32x4*)ws;
    f32x4 s = w[i];
#pragma unroll
    for (int kb = 1; kb < KSPLIT; ++kb) {
        f32x4 v = w[(size_t)kb * stride4 + i];
        s[0] += v[0]; s[1] += v[1]; s[2] += v[2]; s[3] += v[3];
    }
    ((f32x4*)out)[i] = s;
}

extern "C" void kernel_launch(void* const* d_in, const int* in_sizes, int n_in,
                              void* d_out, int out_size, void* d_ws, size_t ws_size,
                              hipStream_t stream) {
    const float* x       = (const float*)d_in[0];
    const float* weight  = (const float*)d_in[1];
    const int*   indices = (const int*)d_in[2];
    float*       out     = (float*)d_out;
    float*       ws      = (float*)d_ws;

    const int R  = in_sizes[2];                   // 4403
    const int nb = (R + NTILE - 1) / NTILE;       // 138

    gather_gemm<<<dim3(nb, KSPLIT), dim3(256), 0, stream>>>(weight, x, indices, ws, R);

    const int n4 = (BATCH * R) / 4;
    reduce_partials<<<dim3((n4 + 255) / 256), dim3(256), 0, stream>>>(ws, out, n4, n4);
}